// Round 1
// baseline (1328.680 us; speedup 1.0000x reference)
//
#include <hip/hip_runtime.h>
#include <hip/hip_bf16.h>
#include <math.h>

typedef __bf16 bf_t;
typedef __attribute__((ext_vector_type(8))) __bf16 bf16x8;
typedef __attribute__((ext_vector_type(4))) float floatx4;

#define EMBED 1024
#define HEADS 16
#define HDIM 64
#define HIDDEN 4096
#define BB 2
#define SS 2048
#define MTOT (BB*SS)   /* 4096 rows */
#define LDP 72         /* P-tile LDS row stride (bf16): 144B, 16B-aligned */

__device__ inline floatx4 mfma16(bf16x8 a, bf16x8 b, floatx4 c){
  return __builtin_amdgcn_mfma_f32_16x16x32_bf16(a, b, c, 0, 0, 0);
}

// async global->LDS, 16B per lane; LDS dest must be wave-uniform base (lane lands at base+lane*16)
__device__ inline void gload16(const bf_t* g, bf_t* l){
  __builtin_amdgcn_global_load_lds((const __attribute__((address_space(1))) void*)g,
                                   (__attribute__((address_space(3))) void*)l, 16, 0, 0);
}

// ---------------- elementwise fp32 -> bf16 ----------------
__launch_bounds__(256)
__global__ void cvt_f2b_kernel(const float* __restrict__ in, bf_t* __restrict__ out, int n4){
  int i = blockIdx.x*256 + threadIdx.x;
  if(i < n4){
    const float4 v = *(const float4*)(in + (size_t)i*4);
    bf_t* o = out + (size_t)i*4;
    o[0]=(bf_t)v.x; o[1]=(bf_t)v.y; o[2]=(bf_t)v.z; o[3]=(bf_t)v.w;
  }
}

// ---------------- transpose fp32[R,C] -> bf16[C,R], batched over z ----------------
__launch_bounds__(256)
__global__ void transpose_f2b(const float* __restrict__ in, bf_t* __restrict__ out, int R, int C){
  __shared__ bf_t tile[32][33];
  const int z = blockIdx.z;
  in  += (size_t)z*R*C;
  out += (size_t)z*R*C;
  const int c0 = blockIdx.x*32, r0 = blockIdx.y*32;
  const int tx = threadIdx.x & 31, ty = threadIdx.x >> 5;
  #pragma unroll
  for(int i=0;i<4;i++)
    tile[ty + i*8][tx] = (bf_t)in[(size_t)(r0+ty+i*8)*C + c0 + tx];
  __syncthreads();
  #pragma unroll
  for(int i=0;i<4;i++)
    out[(size_t)(c0+ty+i*8)*R + r0 + tx] = tile[tx][ty+i*8];
}

// ---------------- transpose bf16[R,C] -> bf16[C,R], batched over z (for v) ----------------
__launch_bounds__(256)
__global__ void transpose_b2b(const bf_t* __restrict__ in, bf_t* __restrict__ out, int R, int C){
  __shared__ bf_t tile[32][33];
  const int z = blockIdx.z;
  in  += (size_t)z*R*C;
  out += (size_t)z*R*C;
  const int c0 = blockIdx.x*32, r0 = blockIdx.y*32;
  const int tx = threadIdx.x & 31, ty = threadIdx.x >> 5;
  #pragma unroll
  for(int i=0;i<4;i++)
    tile[ty + i*8][tx] = in[(size_t)(r0+ty+i*8)*C + c0 + tx];
  __syncthreads();
  #pragma unroll
  for(int i=0;i<4;i++)
    out[(size_t)(c0+ty+i*8)*R + r0 + tx] = tile[tx][ty+i*8];
}

// ---------------- 128x128 GEMM (m97 structure): C[M,N] = A[M,K](bf16) @ BT[N,K]^T --------
// mode 0: out bf16 = acc + bias
// mode 1: out f32  = acc + bias + resid[row*N+col]
// mode 2: out bf16 = gelu(acc + bias)
__launch_bounds__(256)
__global__ void gemm128_kernel(const bf_t* __restrict__ A, const bf_t* __restrict__ BT,
                               const float* __restrict__ bias, const float* __restrict__ resid,
                               float* __restrict__ outF, bf_t* __restrict__ outB,
                               int M, int N, int K, int mode){
  // linear layout mandatory for global_load_lds (no padding)
  __shared__ __attribute__((aligned(16))) bf_t ldsA[128*32];
  __shared__ __attribute__((aligned(16))) bf_t ldsB[128*32];
  const int m0 = blockIdx.y*128, n0 = blockIdx.x*128;
  const int t = threadIdx.x, w = t>>6, lane = t&63;
  const int ln = lane&15, q4 = lane>>4;
  const int wr = w>>1, wc = w&1;         // wave grid 2x2, each wave owns 64x64
  floatx4 acc[4][4] = {};

  // staging: wave w stages rows [w*32, w*32+32) of each tile, 2 instrs of 16 rows
  const int srow = lane>>2;              // 0..15
  const int skc  = (lane&3)*8;           // element offset within 32-wide K slab
  const bf_t* Ag = A  + (size_t)(m0 + w*32 + srow)*K + skc;
  const bf_t* Bg = BT + (size_t)(n0 + w*32 + srow)*K + skc;
  bf_t* Al = &ldsA[(w*32)*32];
  bf_t* Bl = &ldsB[(w*32)*32];
  const size_t rstep = (size_t)16*K;

  for(int k0=0;k0<K;k0+=32){
    __syncthreads();                      // previous iteration's reads done
    gload16(Ag + k0,         Al);
    gload16(Ag + rstep + k0, Al + 16*32);
    gload16(Bg + k0,         Bl);
    gload16(Bg + rstep + k0, Bl + 16*32);
    __syncthreads();                      // vmcnt(0) drained by barrier semantics
    bf16x8 a[4], bb[4];
    #pragma unroll
    for(int m=0;m<4;m++) a[m]  = *(const bf16x8*)&ldsA[(wr*64 + m*16 + ln)*32 + q4*8];
    #pragma unroll
    for(int n=0;n<4;n++) bb[n] = *(const bf16x8*)&ldsB[(wc*64 + n*16 + ln)*32 + q4*8];
    #pragma unroll
    for(int m=0;m<4;m++){
      #pragma unroll
      for(int n=0;n<4;n++){
        acc[m][n] = mfma16(a[m], bb[n], acc[m][n]);
      }
    }
  }

  #pragma unroll
  for(int n=0;n<4;n++){
    const int col = n0 + wc*64 + n*16 + ln;
    const float bsv = bias ? bias[col] : 0.f;
    #pragma unroll
    for(int m=0;m<4;m++){
      #pragma unroll
      for(int r=0;r<4;r++){
        const int row = m0 + wr*64 + m*16 + q4*4 + r;
        float c = acc[m][n][r] + bsv;
        const size_t idx = (size_t)row*N + col;
        if(mode == 1){
          outF[idx] = c + resid[idx];
        } else if(mode == 2){
          const float g = 0.5f*c*(1.0f + erff(c*0.70710678118f));
          outB[idx] = (bf_t)g;
        } else {
          outB[idx] = (bf_t)c;
        }
      }
    }
  }
}

// ---------------- attn pass 1: per-row online max + exp-sum (no score traffic) ----------
// scores s = (q.k)/8 computed with the SAME mfma sequence as pass 2 -> bit-identical.
__launch_bounds__(256)
__global__ void attn_stats_kernel(const bf_t* __restrict__ q, const bf_t* __restrict__ k,
                                  float* __restrict__ statsM, float* __restrict__ statsI){
  const int bh = blockIdx.y;
  const int b = bh >> 4, h = bh & 15;
  const int q0 = blockIdx.x * 64;
  const int t = threadIdx.x, w = t>>6, lane = t&63;
  const int ln = lane&15, q4 = lane>>4;

  const size_t qbase = ((size_t)(b*SS + q0 + w*16 + ln))*EMBED + h*HDIM + q4*8;
  const bf16x8 a0 = *(const bf16x8*)(q + qbase);
  const bf16x8 a1 = *(const bf16x8*)(q + qbase + 32);

  float mrun[4] = {-1e30f,-1e30f,-1e30f,-1e30f};
  float srun[4] = {0.f,0.f,0.f,0.f};

  for(int k0=0;k0<SS;k0+=128){
    floatx4 acc[8];
    #pragma unroll
    for(int j=0;j<8;j++){
      const size_t kbase = ((size_t)(b*SS + k0 + j*16 + ln))*EMBED + h*HDIM + q4*8;
      const bf16x8 b0 = *(const bf16x8*)(k + kbase);
      const bf16x8 b1 = *(const bf16x8*)(k + kbase + 32);
      floatx4 z = {0.f,0.f,0.f,0.f};
      acc[j] = mfma16(a0, b0, z);
      acc[j] = mfma16(a1, b1, acc[j]);
    }
    #pragma unroll
    for(int r=0;r<4;r++){
      float tm = -1e30f;
      #pragma unroll
      for(int j=0;j<8;j++) tm = fmaxf(tm, acc[j][r]);
      tm *= 0.125f;                              // exact (pow2 scale)
      #pragma unroll
      for(int o=1;o<16;o<<=1) tm = fmaxf(tm, __shfl_xor(tm, o));
      const float mnew = fmaxf(mrun[r], tm);
      float ts = 0.f;
      #pragma unroll
      for(int j=0;j<8;j++) ts += expf(acc[j][r]*0.125f - mnew);
      #pragma unroll
      for(int o=1;o<16;o<<=1) ts += __shfl_xor(ts, o);
      srun[r] = srun[r]*expf(mrun[r]-mnew) + ts;
      mrun[r] = mnew;
    }
  }
  if(ln == 0){
    #pragma unroll
    for(int r=0;r<4;r++){
      const int row = q0 + w*16 + q4*4 + r;
      statsM[(size_t)bh*SS + row] = mrun[r];
      statsI[(size_t)bh*SS + row] = 1.0f / srun[r];
    }
  }
}

// ---------------- attn pass 2: recompute scores, write normalized attn (fp32, once),
// and do PV in the same kernel via an LDS P-tile -------------------------------------
__launch_bounds__(256)
__global__ void attn_pv_kernel(const bf_t* __restrict__ q, const bf_t* __restrict__ k,
                               const bf_t* __restrict__ vT,
                               const float* __restrict__ statsM, const float* __restrict__ statsI,
                               float* __restrict__ attn, bf_t* __restrict__ attn_out){
  __shared__ __attribute__((aligned(16))) bf_t ldsP[64*LDP];
  const int bh = blockIdx.y;
  const int b = bh >> 4, h = bh & 15;
  const int q0 = blockIdx.x * 64;
  const int t = threadIdx.x, w = t>>6, lane = t&63;
  const int ln = lane&15, q4 = lane>>4;

  const size_t qbase = ((size_t)(b*SS + q0 + w*16 + ln))*EMBED + h*HDIM + q4*8;
  const bf16x8 a0 = *(const bf16x8*)(q + qbase);
  const bf16x8 a1 = *(const bf16x8*)(q + qbase + 32);

  float mrow[4], irow[4];
  #pragma unroll
  for(int r=0;r<4;r++){
    const int row = q0 + w*16 + q4*4 + r;
    mrow[r] = statsM[(size_t)bh*SS + row];
    irow[r] = statsI[(size_t)bh*SS + row];
  }

  floatx4 accP[4] = {};
  float* attnBase = attn + (size_t)bh*SS*SS;
  const bf_t* Vb = vT + (size_t)bh*HDIM*SS;

  for(int k0=0;k0<SS;k0+=64){
    // --- scores for this 64-wide K tile (same mfma sequence as stats pass) ---
    floatx4 s[4];
    #pragma unroll
    for(int j=0;j<4;j++){
      const size_t kbase = ((size_t)(b*SS + k0 + j*16 + ln))*EMBED + h*HDIM + q4*8;
      const bf16x8 b0 = *(const bf16x8*)(k + kbase);
      const bf16x8 b1 = *(const bf16x8*)(k + kbase + 32);
      floatx4 z = {0.f,0.f,0.f,0.f};
      s[j] = mfma16(a0, b0, z);
      s[j] = mfma16(a1, b1, s[j]);
    }
    __syncthreads();   // previous tile's P reads complete before overwrite
    #pragma unroll
    for(int j=0;j<4;j++){
      #pragma unroll
      for(int r=0;r<4;r++){
        const float p = expf(s[j][r]*0.125f - mrow[r]) * irow[r];
        attnBase[(size_t)(q0 + w*16 + q4*4 + r)*SS + k0 + j*16 + ln] = p;  // final value, written once
        ldsP[(w*16 + q4*4 + r)*LDP + j*16 + ln] = (bf_t)p;
      }
    }
    __syncthreads();
    // --- PV: accP[n] += P(16q x 64k) @ V^T(64d x 64k)^T ---
    #pragma unroll
    for(int c=0;c<2;c++){
      const bf16x8 ap = *(const bf16x8*)&ldsP[(w*16 + ln)*LDP + c*32 + q4*8];
      #pragma unroll
      for(int n=0;n<4;n++){
        const bf16x8 bv = *(const bf16x8*)(Vb + (size_t)(n*16+ln)*SS + k0 + c*32 + q4*8);
        accP[n] = mfma16(ap, bv, accP[n]);
      }
    }
  }

  #pragma unroll
  for(int n=0;n<4;n++){
    #pragma unroll
    for(int r=0;r<4;r++){
      const int row = q0 + w*16 + q4*4 + r;
      attn_out[((size_t)(b*SS+row))*EMBED + h*HDIM + n*16 + ln] = (bf_t)accP[n][r];
    }
  }
}

// ---------------- layernorm over 1024, optional f32 + bf16 outputs ----------------
__launch_bounds__(256)
__global__ void ln_kernel(const float* __restrict__ in, const float* __restrict__ gamma,
                          const float* __restrict__ beta, float* __restrict__ outF,
                          bf_t* __restrict__ outB){
  __shared__ float sred[4];
  const size_t row = blockIdx.x;
  const float* p = in + row*EMBED;
  const int t = threadIdx.x;
  const float4 v = *(const float4*)(p + t*4);
  float s = v.x+v.y+v.z+v.w;
  #pragma unroll
  for(int o=32;o>0;o>>=1) s += __shfl_xor(s, o);
  if((t&63)==0) sred[t>>6]=s;
  __syncthreads();
  const float mu = (sred[0]+sred[1]+sred[2]+sred[3]) * (1.0f/EMBED);
  __syncthreads();
  const float dx=v.x-mu, dy=v.y-mu, dz=v.z-mu, dw=v.w-mu;
  float s2 = dx*dx+dy*dy+dz*dz+dw*dw;
  #pragma unroll
  for(int o=32;o>0;o>>=1) s2 += __shfl_xor(s2, o);
  if((t&63)==0) sred[t>>6]=s2;
  __syncthreads();
  const float var = (sred[0]+sred[1]+sred[2]+sred[3]) * (1.0f/EMBED);
  const float rstd = rsqrtf(var + 1e-5f);
  const float4 g = *(const float4*)(gamma + t*4);
  const float4 bt = *(const float4*)(beta + t*4);
  float4 o;
  o.x = dx*rstd*g.x + bt.x;
  o.y = dy*rstd*g.y + bt.y;
  o.z = dz*rstd*g.z + bt.z;
  o.w = dw*rstd*g.w + bt.w;
  if(outF) *(float4*)(outF + row*EMBED + t*4) = o;
  if(outB){
    bf_t* ob = outB + row*EMBED + t*4;
    ob[0]=(bf_t)o.x; ob[1]=(bf_t)o.y; ob[2]=(bf_t)o.z; ob[3]=(bf_t)o.w;
  }
}

extern "C" void kernel_launch(void* const* d_in, const int* in_sizes, int n_in,
                              void* d_out, int out_size, void* d_ws, size_t ws_size,
                              hipStream_t stream){
  const float* x  = (const float*)d_in[0];
  const float* Wq = (const float*)d_in[1];
  const float* bq = (const float*)d_in[2];
  const float* Wk = (const float*)d_in[3];
  const float* bk = (const float*)d_in[4];
  const float* Wv = (const float*)d_in[5];
  const float* bv = (const float*)d_in[6];
  const float* Wo = (const float*)d_in[7];
  const float* bo = (const float*)d_in[8];
  const float* W1 = (const float*)d_in[9];
  const float* b1 = (const float*)d_in[10];
  const float* W2 = (const float*)d_in[11];
  const float* b2 = (const float*)d_in[12];
  const float* gamma = (const float*)d_in[13];
  const float* beta  = (const float*)d_in[14];

  float* outp = (float*)d_out;                      // [4096,1024]
  float* attn = outp + (size_t)MTOT*EMBED;          // [32,2048,2048]

  char* ws = (char*)d_ws;
  size_t off = 0;
  auto alloc = [&](size_t bytes)->void*{
    void* p = ws + off; off += (bytes + 255) & ~(size_t)255; return p;
  };
  bf_t* xb  = (bf_t*)alloc((size_t)MTOT*EMBED*2);
  bf_t* WqT = (bf_t*)alloc((size_t)EMBED*EMBED*2);
  bf_t* WkT = (bf_t*)alloc((size_t)EMBED*EMBED*2);
  bf_t* WvT = (bf_t*)alloc((size_t)EMBED*EMBED*2);
  bf_t* WoT = (bf_t*)alloc((size_t)EMBED*EMBED*2);
  bf_t* W1T = (bf_t*)alloc((size_t)EMBED*HIDDEN*2);
  bf_t* W2T = (bf_t*)alloc((size_t)HIDDEN*EMBED*2);
  bf_t* qb  = (bf_t*)alloc((size_t)MTOT*EMBED*2);
  bf_t* kb  = (bf_t*)alloc((size_t)MTOT*EMBED*2);
  bf_t* vb  = (bf_t*)alloc((size_t)MTOT*EMBED*2);
  bf_t* vT  = (bf_t*)alloc((size_t)MTOT*EMBED*2);
  bf_t* ao  = (bf_t*)alloc((size_t)MTOT*EMBED*2);  // attn_out bf16
  float* y  = (float*)alloc((size_t)MTOT*EMBED*4); // pre-LN fp32 (reused)
  float* hf = (float*)alloc((size_t)MTOT*EMBED*4); // h fp32
  bf_t* hb  = (bf_t*)alloc((size_t)MTOT*EMBED*2);  // h bf16
  bf_t* g   = (bf_t*)alloc((size_t)MTOT*HIDDEN*2); // gelu out bf16
  float* statsM = (float*)alloc((size_t)BB*HEADS*SS*4); // row max (scaled scores)
  float* statsI = (float*)alloc((size_t)BB*HEADS*SS*4); // 1/sum
  (void)ws_size; (void)n_in; (void)in_sizes; (void)out_size;

  // 1) convert x -> bf16
  cvt_f2b_kernel<<<dim3((MTOT*EMBED/4 + 255)/256), 256, 0, stream>>>(x, xb, MTOT*EMBED/4);
  // 2) transpose+convert weights to [N,K] bf16
  transpose_f2b<<<dim3(EMBED/32, EMBED/32, 1), 256, 0, stream>>>(Wq, WqT, EMBED, EMBED);
  transpose_f2b<<<dim3(EMBED/32, EMBED/32, 1), 256, 0, stream>>>(Wk, WkT, EMBED, EMBED);
  transpose_f2b<<<dim3(EMBED/32, EMBED/32, 1), 256, 0, stream>>>(Wv, WvT, EMBED, EMBED);
  transpose_f2b<<<dim3(EMBED/32, EMBED/32, 1), 256, 0, stream>>>(Wo, WoT, EMBED, EMBED);
  transpose_f2b<<<dim3(HIDDEN/32, EMBED/32, 1), 256, 0, stream>>>(W1, W1T, EMBED, HIDDEN);
  transpose_f2b<<<dim3(EMBED/32, HIDDEN/32, 1), 256, 0, stream>>>(W2, W2T, HIDDEN, EMBED);
  // 3) QKV projections -> bf16 (128x128 m97-structure GEMM)
  gemm128_kernel<<<dim3(EMBED/128, MTOT/128), 256, 0, stream>>>(xb, WqT, bq, nullptr, nullptr, qb, MTOT, EMBED, EMBED, 0);
  gemm128_kernel<<<dim3(EMBED/128, MTOT/128), 256, 0, stream>>>(xb, WkT, bk, nullptr, nullptr, kb, MTOT, EMBED, EMBED, 0);
  gemm128_kernel<<<dim3(EMBED/128, MTOT/128), 256, 0, stream>>>(xb, WvT, bv, nullptr, nullptr, vb, MTOT, EMBED, EMBED, 0);
  // 4) transpose v per batch: [2048,1024] -> [1024,2048]  (vT[b,h,d,s])
  transpose_b2b<<<dim3(EMBED/32, SS/32, BB), 256, 0, stream>>>(vb, vT, SS, EMBED);
  // 5) attention pass 1: row stats (max, 1/sum) — no score matrix traffic
  attn_stats_kernel<<<dim3(SS/64, BB*HEADS), 256, 0, stream>>>(qb, kb, statsM, statsI);
  // 6) attention pass 2: recompute scores, write normalized attn once + PV
  attn_pv_kernel<<<dim3(SS/64, BB*HEADS), 256, 0, stream>>>(qb, kb, vT, statsM, statsI, attn, ao);
  // 7) O-proj + bias + residual(x) -> y fp32
  gemm128_kernel<<<dim3(EMBED/128, MTOT/128), 256, 0, stream>>>(ao, WoT, bo, x, y, nullptr, MTOT, EMBED, EMBED, 1);
  // 8) LN1 -> hf (fp32) + hb (bf16)
  ln_kernel<<<dim3(MTOT), 256, 0, stream>>>(y, gamma, beta, hf, hb);
  // 9) MLP1 + gelu -> g bf16
  gemm128_kernel<<<dim3(HIDDEN/128, MTOT/128), 256, 0, stream>>>(hb, W1T, b1, nullptr, nullptr, g, MTOT, HIDDEN, EMBED, 2);
  // 10) MLP2 + bias + residual(hf) -> y fp32 (reuse)
  gemm128_kernel<<<dim3(EMBED/128, MTOT/128), 256, 0, stream>>>(g, W2T, b2, hf, y, nullptr, MTOT, EMBED, HIDDEN, 1);
  // 11) LN2 -> d_out
  ln_kernel<<<dim3(MTOT), 256, 0, stream>>>(y, gamma, beta, outp, nullptr);
}